// Round 1
// baseline (5246.040 us; speedup 1.0000x reference)
//
#include <hip/hip_runtime.h>
#include <math.h>

#define NSAMP 32768      // time-domain samples
#define MH    16384      // half-size complex FFT length
#define LFREQ 32770      // rfft concat(re,im) length = 2*(NSAMP/2+1)
#define NRE   16385      // number of rfft bins
#define NB    64         // batches
#define NA    512        // atoms
#define NITER 64
#define RSTR  32772      // padded row stride (multiple of 4) for res/rec in ws

// dots kernel tiling
#define KS 32            // k slices (grid.x)
#define NT 16            // atom tiles (grid.y)
#define BN 32            // atoms per tile
#define KC 128           // k chunk (floats) staged in LDS
#define NCHUNK 257       // ceil(32770/128)
#define USLICE 4         // update kernel k-split

__device__ __forceinline__ int rev14(int v) { return (int)(__brev((unsigned)v) >> 18); }

// ---------------- forward rfft: x[b][32768] -> res[b][32770] (re|im concat) ----------------
__global__ __launch_bounds__(256) void fft_fwd_kernel(const float* __restrict__ x,
                                                      float* __restrict__ res) {
  extern __shared__ float2 s[];   // 16384 complex = 128 KB
  const int b = blockIdx.x, t = threadIdx.x;
  const float2* xrow = (const float2*)(x + (size_t)b * NSAMP);
  // pack z[m] = x[2m] + i x[2m+1], bit-reversed load
  for (int m = t; m < MH; m += 256) s[rev14(m)] = xrow[m];
  __syncthreads();
  // radix-2 DIT, twiddle e^{-i*2pi*pos/len}
  for (int len = 2; len <= MH; len <<= 1) {
    const int half = len >> 1;
    const float fac = 6.283185307179586f / (float)len;
    for (int j = t; j < MH / 2; j += 256) {
      const int blk = j / half, pos = j - blk * half;
      const int i0 = blk * len + pos, i1 = i0 + half;
      float sn, cs; sincosf(fac * (float)pos, &sn, &cs);
      const float2 u = s[i0], v = s[i1];
      const float tr = cs * v.x + sn * v.y;   // (cs - i sn)*(vx + i vy)
      const float ti = cs * v.y - sn * v.x;
      s[i0] = make_float2(u.x + tr, u.y + ti);
      s[i1] = make_float2(u.x - tr, u.y - ti);
    }
    __syncthreads();
  }
  // unpack half-size FFT -> rfft bins
  float* rr = res + (size_t)b * RSTR;
  const float fac2 = 6.283185307179586f / (float)NSAMP;
  for (int k = t; k < MH; k += 256) {
    if (k == 0) {
      const float2 z0 = s[0];
      rr[0] = z0.x + z0.y;      rr[NRE] = 0.f;        // DC (real)
      rr[MH] = z0.x - z0.y;     rr[NRE + MH] = 0.f;   // Nyquist (real)
    } else {
      const float2 zk = s[k], zm = s[MH - k];
      const float xer = 0.5f * (zk.x + zm.x), xei = 0.5f * (zk.y - zm.y);
      const float p = 0.5f * (zk.y + zm.y);    //  D.im/2,  D = Zk - conj(Zm)
      const float q = -0.5f * (zk.x - zm.x);   // -D.re/2
      float sn, cs; sincosf(fac2 * (float)k, &sn, &cs);
      rr[k]       = xer + cs * p + sn * q;
      rr[NRE + k] = xei + cs * q - sn * p;
    }
  }
}

// ---------------- inverse rfft: rec[b][32770] -> out[b][32768] ----------------
__global__ __launch_bounds__(256) void fft_inv_kernel(const float* __restrict__ rec,
                                                      float* __restrict__ out) {
  extern __shared__ float2 s[];
  const int b = blockIdx.x, t = threadIdx.x;
  const float* rr = rec + (size_t)b * RSTR;
  const float fac2 = 6.283185307179586f / (float)NSAMP;
  for (int k = t; k < MH; k += 256) {
    float2 z;
    if (k == 0) {
      // c2r ignores imag of DC & Nyquist (pocketfft semantics)
      const float a0 = rr[0], aM = rr[MH];
      z = make_float2(0.5f * (a0 + aM), 0.5f * (a0 - aM));
    } else {
      const float xr_ = rr[k],       xi_ = rr[NRE + k];
      const float mr  = rr[MH - k],  mi  = rr[NRE + MH - k];
      const float xer = 0.5f * (xr_ + mr), xei = 0.5f * (xi_ - mi);
      const float er  = 0.5f * (xr_ - mr), ei  = 0.5f * (xi_ + mi);
      float sn, cs; sincosf(fac2 * (float)k, &sn, &cs);
      const float xor_ = cs * er - sn * ei;   // e^{+i th} * E
      const float xoi  = cs * ei + sn * er;
      z = make_float2(xer - xoi, xei + xor_);
    }
    s[rev14(k)] = z;
  }
  __syncthreads();
  // inverse radix-2 DIT, twiddle e^{+i*2pi*pos/len}
  for (int len = 2; len <= MH; len <<= 1) {
    const int half = len >> 1;
    const float fac = 6.283185307179586f / (float)len;
    for (int j = t; j < MH / 2; j += 256) {
      const int blk = j / half, pos = j - blk * half;
      const int i0 = blk * len + pos, i1 = i0 + half;
      float sn, cs; sincosf(fac * (float)pos, &sn, &cs);
      const float2 u = s[i0], v = s[i1];
      const float tr = cs * v.x - sn * v.y;
      const float ti = cs * v.y + sn * v.x;
      s[i0] = make_float2(u.x + tr, u.y + ti);
      s[i1] = make_float2(u.x - tr, u.y - ti);
    }
    __syncthreads();
  }
  const float inv = 1.0f / (float)MH;
  float2* orow = (float2*)(out + (size_t)b * NSAMP);
  for (int m = t; m < MH; m += 256) {
    const float2 z = s[m];
    orow[m] = make_float2(z.x * inv, z.y * inv);   // x[2m], x[2m+1]
  }
}

// ---------------- atom norms: rnorm[a] = 1/||atoms[a]|| ----------------
__global__ __launch_bounds__(256) void norm_kernel(const float* __restrict__ atoms,
                                                   float* __restrict__ rnorm) {
  const int a = blockIdx.x, t = threadIdx.x;
  const float2* row = (const float2*)(atoms + (size_t)a * LFREQ);
  float ss = 0.f;
  for (int i = t; i < LFREQ / 2; i += 256) {  // 16385 float2 exactly
    const float2 v = row[i];
    ss += v.x * v.x + v.y * v.y;
  }
  __shared__ float red[256];
  red[t] = ss; __syncthreads();
  for (int st = 128; st > 0; st >>= 1) {
    if (t < st) red[t] += red[t + st];
    __syncthreads();
  }
  if (t == 0) rnorm[a] = 1.0f / sqrtf(red[0]);
}

// ---------------- dots: partials[s][b][a] = sum_{k in slice s} res[b][k]*atoms[a][k] ----------------
__global__ __launch_bounds__(256) void dots_kernel(const float* __restrict__ res,
                                                   const float* __restrict__ atoms,
                                                   float* __restrict__ partials) {
  __shared__ float res_s[NB][KC + 4];   // +4 pad vs bank conflicts
  __shared__ float atm_s[BN][KC + 4];
  const int slice = blockIdx.x;   // 0..KS-1
  const int atile = blockIdx.y;   // 0..NT-1
  const int t = threadIdx.x;
  const int tk = t & 1;
  const int tau = t >> 1;                 // 0..127
  const int acol = (tau & 7) << 2;        // 0..28  (atom sub-tile)
  const int brow = ((tau >> 3) & 15) << 2; // 0..60 (batch sub-tile)
  float acc[4][4] = {};

  for (int c = slice; c < NCHUNK; c += KS) {
    const int kb = c * KC;
    __syncthreads();
    // stage res chunk: 64 rows x 128 cols = 4096 float2
    #pragma unroll
    for (int i = 0; i < 16; ++i) {
      const int f = i * 256 + t;
      const int row = f >> 6, col2 = f & 63;
      const int k = kb + (col2 << 1);
      float2 v = make_float2(0.f, 0.f);
      if (k < LFREQ) v = *(const float2*)(res + (size_t)row * RSTR + k);
      *(float2*)&res_s[row][col2 << 1] = v;
    }
    // stage atom chunk: 32 rows x 128 cols = 2048 float2
    #pragma unroll
    for (int i = 0; i < 8; ++i) {
      const int f = i * 256 + t;
      const int row = f >> 6, col2 = f & 63;
      const int k = kb + (col2 << 1);
      float2 v = make_float2(0.f, 0.f);
      if (k < LFREQ) v = *(const float2*)(atoms + (size_t)(atile * BN + row) * LFREQ + k);
      *(float2*)&atm_s[row][col2 << 1] = v;
    }
    __syncthreads();
    // compute: 4b x 4a register tile, 2-way k split
    for (int kq = tk; kq < KC / 4; kq += 2) {
      float4 r4[4], a4[4];
      #pragma unroll
      for (int i = 0; i < 4; ++i) r4[i] = *(const float4*)&res_s[brow + i][kq << 2];
      #pragma unroll
      for (int j = 0; j < 4; ++j) a4[j] = *(const float4*)&atm_s[acol + j][kq << 2];
      #pragma unroll
      for (int i = 0; i < 4; ++i)
        #pragma unroll
        for (int j = 0; j < 4; ++j)
          acc[i][j] += r4[i].x * a4[j].x + r4[i].y * a4[j].y +
                       r4[i].z * a4[j].z + r4[i].w * a4[j].w;
    }
  }
  __syncthreads();
  // reduce the 2-way k split through LDS (reuse res_s: need 256*16 = 4096 floats)
  float* red = &res_s[0][0];
  #pragma unroll
  for (int u = 0; u < 16; ++u) red[t * 16 + u] = acc[u >> 2][u & 3];
  __syncthreads();
  for (int o = t; o < 2048; o += 256) {
    const int tau2 = o >> 4, u = o & 15;
    const float v = red[(tau2 * 2) * 16 + u] + red[(tau2 * 2 + 1) * 16 + u];
    const int i = u >> 2, j = u & 3;
    const int bb = ((tau2 >> 3) & 15) * 4 + i;
    const int aa = atile * BN + ((tau2 & 7) << 2) + j;
    partials[((size_t)slice * NB + bb) * NA + aa] = v;
  }
}

// ---------------- argmax (redundant per slice) + res/rec update ----------------
__global__ __launch_bounds__(256) void update_kernel(float* __restrict__ res,
                                                     float* __restrict__ rec,
                                                     const float* __restrict__ atoms,
                                                     const float* __restrict__ rnorm,
                                                     const float* __restrict__ partials) {
  const int slice = blockIdx.x;   // 0..USLICE-1
  const int b = blockIdx.y;
  const int t = threadIdx.x;
  // reduce partials over k-slices, scale by rnorm, find argmax (first-max tie-break)
  __shared__ float svals[256];
  __shared__ int sidx[256];
  float best = -INFINITY; int bi = 0;
  for (int a = t; a < NA; a += 256) {
    float d = 0.f;
    #pragma unroll 4
    for (int s = 0; s < KS; ++s) d += partials[((size_t)s * NB + b) * NA + a];
    d *= rnorm[a];
    if (d > best) { best = d; bi = a; }   // ascending a -> keeps smallest idx on ties
  }
  svals[t] = best; sidx[t] = bi; __syncthreads();
  for (int st = 128; st > 0; st >>= 1) {
    if (t < st) {
      const float v2 = svals[t + st]; const int i2 = sidx[t + st];
      if (v2 > svals[t] || (v2 == svals[t] && i2 < sidx[t])) { svals[t] = v2; sidx[t] = i2; }
    }
    __syncthreads();
  }
  const int idx = sidx[0];
  const float rn = rnorm[idx];
  // update: best = an[idx] .* res ; res -= best ; rec += best   (this block's k-slice)
  const float2* arow = (const float2*)(atoms + (size_t)idx * LFREQ);
  float2* rrow = (float2*)(res + (size_t)b * RSTR);
  float2* crow = (float2*)(rec + (size_t)b * RSTR);
  const int i0 = slice * 4097;
  const int i1 = min(i0 + 4097, LFREQ / 2 + 1);   // 16385 float2 total
  for (int i = i0 + t; i < i1; i += 256) {
    const float2 r = rrow[i], a2 = arow[i], cc = crow[i];
    const float bx = a2.x * rn * r.x;
    const float by = a2.y * rn * r.y;
    rrow[i] = make_float2(r.x - bx, r.y - by);
    crow[i] = make_float2(cc.x + bx, cc.y + by);
  }
}

// ---------------- strip padding: res(ws, stride RSTR) -> out2 (contiguous 64x32770) ----------------
__global__ __launch_bounds__(256) void copy_res_kernel(const float* __restrict__ res,
                                                       float* __restrict__ out2) {
  const int b = blockIdx.x, t = threadIdx.x;
  const float* src = res + (size_t)b * RSTR;
  float* dst = out2 + (size_t)b * LFREQ;
  for (int k = t; k < LFREQ; k += 256) dst[k] = src[k];
}

extern "C" void kernel_launch(void* const* d_in, const int* in_sizes, int n_in,
                              void* d_out, int out_size, void* d_ws, size_t ws_size,
                              hipStream_t stream) {
  const float* x = (const float*)d_in[0];      // (64,1,32768)
  const float* atoms = (const float*)d_in[1];  // (1,512,32770)
  float* out = (float*)d_out;

  float* res = (float*)d_ws;                       // 64*32772
  float* rec = res + (size_t)NB * RSTR;            // 64*32772
  float* rnorm = rec + (size_t)NB * RSTR;          // 512
  float* partials = rnorm + NA;                    // 32*64*512

  hipMemsetAsync(rec, 0, (size_t)NB * RSTR * sizeof(float), stream);
  norm_kernel<<<NA, 256, 0, stream>>>(atoms, rnorm);
  fft_fwd_kernel<<<NB, 256, MH * sizeof(float2), stream>>>(x, res);

  for (int it = 0; it < NITER; ++it) {
    dots_kernel<<<dim3(KS, NT), 256, 0, stream>>>(res, atoms, partials);
    update_kernel<<<dim3(USLICE, NB), 256, 0, stream>>>(res, rec, atoms, rnorm, partials);
  }

  fft_inv_kernel<<<NB, 256, MH * sizeof(float2), stream>>>(rec, out);
  copy_res_kernel<<<NB, 256, 0, stream>>>(res, out + (size_t)NB * NSAMP);
}

// Round 2
// 5050.653 us; speedup vs baseline: 1.0387x; 1.0387x over previous
//
#include <hip/hip_runtime.h>
#include <math.h>

#define NSAMP 32768      // time-domain samples
#define MH    16384      // half-size complex FFT length
#define LFREQ 32770      // rfft concat(re,im) length = 2*(NSAMP/2+1)
#define NRE   16385      // number of rfft bins
#define NB    64         // batches
#define NA    512        // atoms
#define NITER 64
#define RSTR  32772      // padded row stride for fp32 res/rec in ws

#define KPS    33280     // bf16 row stride = 65*512 (zero-padded past LFREQ)
#define NSLICE 65        // k-slices for dots (512 k each)
#define USLICE 8         // update kernel k-split

typedef __attribute__((ext_vector_type(8))) short bf16x8;
typedef __attribute__((ext_vector_type(4))) float f32x4;

__device__ __forceinline__ int rev14(int v) { return (int)(__brev((unsigned)v) >> 18); }

__device__ __forceinline__ unsigned short f2bf(float f) {
  unsigned u = __float_as_uint(f);
  u = (u + 0x7fffu + ((u >> 16) & 1u)) >> 16;   // round-to-nearest-even
  return (unsigned short)u;
}
__device__ __forceinline__ float bf2f(unsigned short h) {
  return __uint_as_float(((unsigned)h) << 16);
}

// ---------------- forward rfft: x[b][32768] -> res[b][32770] (re|im concat) ----------------
__global__ __launch_bounds__(1024) void fft_fwd_kernel(const float* __restrict__ x,
                                                       float* __restrict__ res) {
  extern __shared__ float2 s[];   // 16384 complex = 128 KB
  const int b = blockIdx.x, t = threadIdx.x;
  const float2* xrow = (const float2*)(x + (size_t)b * NSAMP);
  // pack z[m] = x[2m] + i x[2m+1]; bit-reverse on the READ side (LDS writes sequential)
  for (int m = t; m < MH; m += 1024) s[m] = xrow[rev14(m)];
  __syncthreads();
  // radix-2 DIT, twiddle e^{-i*2pi*pos/len}
  for (int st = 1; st <= 14; ++st) {
    const int half = 1 << (st - 1);
    const float fac = 3.14159265358979f / (float)half;
    for (int j = t; j < MH / 2; j += 1024) {
      const int blk = j >> (st - 1), pos = j & (half - 1);
      const int i0 = (blk << st) + pos, i1 = i0 + half;
      float sn, cs; __sincosf(fac * (float)pos, &sn, &cs);
      const float2 u = s[i0], v = s[i1];
      const float tr = cs * v.x + sn * v.y;   // (cs - i sn)*(vx + i vy)
      const float ti = cs * v.y - sn * v.x;
      s[i0] = make_float2(u.x + tr, u.y + ti);
      s[i1] = make_float2(u.x - tr, u.y - ti);
    }
    __syncthreads();
  }
  // unpack half-size FFT -> rfft bins
  float* rr = res + (size_t)b * RSTR;
  const float fac2 = 6.283185307179586f / (float)NSAMP;
  for (int k = t; k < MH; k += 1024) {
    if (k == 0) {
      const float2 z0 = s[0];
      rr[0] = z0.x + z0.y;      rr[NRE] = 0.f;        // DC (real)
      rr[MH] = z0.x - z0.y;     rr[NRE + MH] = 0.f;   // Nyquist (real)
    } else {
      const float2 zk = s[k], zm = s[MH - k];
      const float xer = 0.5f * (zk.x + zm.x), xei = 0.5f * (zk.y - zm.y);
      const float p = 0.5f * (zk.y + zm.y);
      const float q = -0.5f * (zk.x - zm.x);
      float sn, cs; __sincosf(fac2 * (float)k, &sn, &cs);
      rr[k]       = xer + cs * p + sn * q;
      rr[NRE + k] = xei + cs * q - sn * p;
    }
  }
}

// ---------------- inverse rfft: rec[b][32770] -> out[b][32768] ----------------
__global__ __launch_bounds__(1024) void fft_inv_kernel(const float* __restrict__ rec,
                                                       float* __restrict__ out) {
  extern __shared__ float2 s[];
  const int b = blockIdx.x, t = threadIdx.x;
  const float* rr = rec + (size_t)b * RSTR;
  const float fac2 = 6.283185307179586f / (float)NSAMP;
  for (int m = t; m < MH; m += 1024) {
    const int k = rev14(m);
    float2 z;
    if (k == 0) {
      const float a0 = rr[0], aM = rr[MH];   // c2r ignores imag of DC & Nyquist
      z = make_float2(0.5f * (a0 + aM), 0.5f * (a0 - aM));
    } else {
      const float xr_ = rr[k],       xi_ = rr[NRE + k];
      const float mr  = rr[MH - k],  mi  = rr[NRE + MH - k];
      const float xer = 0.5f * (xr_ + mr), xei = 0.5f * (xi_ - mi);
      const float er  = 0.5f * (xr_ - mr), ei  = 0.5f * (xi_ + mi);
      float sn, cs; __sincosf(fac2 * (float)k, &sn, &cs);
      const float xor_ = cs * er - sn * ei;   // e^{+i th} * E
      const float xoi  = cs * ei + sn * er;
      z = make_float2(xer - xoi, xei + xor_);
    }
    s[m] = z;   // sequential LDS write, scattered (L2-hot) global read
  }
  __syncthreads();
  for (int st = 1; st <= 14; ++st) {
    const int half = 1 << (st - 1);
    const float fac = 3.14159265358979f / (float)half;
    for (int j = t; j < MH / 2; j += 1024) {
      const int blk = j >> (st - 1), pos = j & (half - 1);
      const int i0 = (blk << st) + pos, i1 = i0 + half;
      float sn, cs; __sincosf(fac * (float)pos, &sn, &cs);
      const float2 u = s[i0], v = s[i1];
      const float tr = cs * v.x - sn * v.y;   // e^{+i th}
      const float ti = cs * v.y + sn * v.x;
      s[i0] = make_float2(u.x + tr, u.y + ti);
      s[i1] = make_float2(u.x - tr, u.y - ti);
    }
    __syncthreads();
  }
  const float inv = 1.0f / (float)MH;
  float2* orow = (float2*)(out + (size_t)b * NSAMP);
  for (int m = t; m < MH; m += 1024) {
    const float2 z = s[m];
    orow[m] = make_float2(z.x * inv, z.y * inv);
  }
}

// ---------------- atom norm + normalized bf16 hi/lo split (rnorm folded in) ----------------
__global__ __launch_bounds__(256) void an_convert_kernel(const float* __restrict__ atoms,
                                                         float* __restrict__ rnorm,
                                                         unsigned short* __restrict__ anH,
                                                         unsigned short* __restrict__ anL) {
  const int a = blockIdx.x, t = threadIdx.x;
  const float* row = atoms + (size_t)a * LFREQ;
  const float2* row2 = (const float2*)row;
  float ss = 0.f;
  for (int i = t; i < LFREQ / 2; i += 256) {   // 16385 float2 exactly
    const float2 v = row2[i];
    ss += v.x * v.x + v.y * v.y;
  }
  __shared__ float red[256];
  red[t] = ss; __syncthreads();
  for (int st = 128; st > 0; st >>= 1) {
    if (t < st) red[t] += red[t + st];
    __syncthreads();
  }
  const float rn = 1.0f / sqrtf(red[0]);
  if (t == 0) rnorm[a] = rn;
  unsigned short* hrow = anH + (size_t)a * KPS;
  unsigned short* lrow = anL + (size_t)a * KPS;
  for (int k = t; k < KPS; k += 256) {
    unsigned short h = 0, l = 0;
    if (k < LFREQ) {
      const float v = row[k] * rn;
      h = f2bf(v);
      l = f2bf(v - bf2f(h));
    }
    hrow[k] = h; lrow[k] = l;
  }
}

// ---------------- initial res -> bf16 hi/lo ----------------
__global__ __launch_bounds__(256) void res_convert_kernel(const float* __restrict__ res,
                                                          unsigned short* __restrict__ resH,
                                                          unsigned short* __restrict__ resL) {
  const int b = blockIdx.x, t = threadIdx.x;
  const float* row = res + (size_t)b * RSTR;
  unsigned short* hrow = resH + (size_t)b * KPS;
  unsigned short* lrow = resL + (size_t)b * KPS;
  for (int k = t; k < KPS; k += 256) {
    unsigned short h = 0, l = 0;
    if (k < LFREQ) {
      const float v = row[k];
      h = f2bf(v);
      l = f2bf(v - bf2f(h));
    }
    hrow[k] = h; lrow[k] = l;
  }
}

// ---------------- dots via split-bf16 MFMA ----------------
// partials[s][b][a] = sum_{k in slice s} res[b][k] * an[a][k]   (an pre-normalized)
// C = resH*anH + resH*anL + resL*anH  (lo*lo dropped: 2^-18 relative — negligible for argmax)
__global__ __launch_bounds__(256) void dots_mfma_kernel(const unsigned short* __restrict__ resH,
                                                        const unsigned short* __restrict__ resL,
                                                        const unsigned short* __restrict__ anH,
                                                        const unsigned short* __restrict__ anL,
                                                        float* __restrict__ partials) {
  const int slice = blockIdx.x;   // 0..NSLICE-1, 512 k each
  const int atile = blockIdx.y;   // 0..7, 64 atoms each
  const int t = threadIdx.x;
  const int wv = t >> 6, lane = t & 63;
  const int r16 = lane & 15;      // A row / B col within 16-tile
  const int kg  = lane >> 4;      // k-group of 8
  const size_t kbase = (size_t)slice * 512 + (size_t)kg * 8;

  const unsigned short* pAH = resH + (size_t)(wv * 16 + r16) * KPS + kbase;
  const unsigned short* pAL = resL + (size_t)(wv * 16 + r16) * KPS + kbase;
  const unsigned short* pBH = anH + (size_t)(atile * 64 + r16) * KPS + kbase;
  const unsigned short* pBL = anL + (size_t)(atile * 64 + r16) * KPS + kbase;

  f32x4 acc0 = {0.f, 0.f, 0.f, 0.f}, acc1 = acc0, acc2 = acc0, acc3 = acc0;

  #pragma unroll 2
  for (int s = 0; s < 16; ++s) {
    const int ko = s * 32;
    const bf16x8 aH = *(const bf16x8*)(pAH + ko);
    const bf16x8 aL = *(const bf16x8*)(pAL + ko);
    const bf16x8 b0H = *(const bf16x8*)(pBH + ko);
    const bf16x8 b0L = *(const bf16x8*)(pBL + ko);
    const bf16x8 b1H = *(const bf16x8*)(pBH + (size_t)16 * KPS + ko);
    const bf16x8 b1L = *(const bf16x8*)(pBL + (size_t)16 * KPS + ko);
    const bf16x8 b2H = *(const bf16x8*)(pBH + (size_t)32 * KPS + ko);
    const bf16x8 b2L = *(const bf16x8*)(pBL + (size_t)32 * KPS + ko);
    const bf16x8 b3H = *(const bf16x8*)(pBH + (size_t)48 * KPS + ko);
    const bf16x8 b3L = *(const bf16x8*)(pBL + (size_t)48 * KPS + ko);
    acc0 = __builtin_amdgcn_mfma_f32_16x16x32_bf16(aH, b0H, acc0, 0, 0, 0);
    acc1 = __builtin_amdgcn_mfma_f32_16x16x32_bf16(aH, b1H, acc1, 0, 0, 0);
    acc2 = __builtin_amdgcn_mfma_f32_16x16x32_bf16(aH, b2H, acc2, 0, 0, 0);
    acc3 = __builtin_amdgcn_mfma_f32_16x16x32_bf16(aH, b3H, acc3, 0, 0, 0);
    acc0 = __builtin_amdgcn_mfma_f32_16x16x32_bf16(aH, b0L, acc0, 0, 0, 0);
    acc1 = __builtin_amdgcn_mfma_f32_16x16x32_bf16(aH, b1L, acc1, 0, 0, 0);
    acc2 = __builtin_amdgcn_mfma_f32_16x16x32_bf16(aH, b2L, acc2, 0, 0, 0);
    acc3 = __builtin_amdgcn_mfma_f32_16x16x32_bf16(aH, b3L, acc3, 0, 0, 0);
    acc0 = __builtin_amdgcn_mfma_f32_16x16x32_bf16(aL, b0H, acc0, 0, 0, 0);
    acc1 = __builtin_amdgcn_mfma_f32_16x16x32_bf16(aL, b1H, acc1, 0, 0, 0);
    acc2 = __builtin_amdgcn_mfma_f32_16x16x32_bf16(aL, b2H, acc2, 0, 0, 0);
    acc3 = __builtin_amdgcn_mfma_f32_16x16x32_bf16(aL, b3H, acc3, 0, 0, 0);
  }
  // D layout: row=(lane>>4)*4+j, col=lane&15  [measured: learn_hip m89/m91]
  const int brow = wv * 16 + kg * 4;
  const int acol = atile * 64 + r16;
  float* pp = partials + ((size_t)slice * NB + brow) * NA + acol;
  #pragma unroll
  for (int j = 0; j < 4; ++j) {
    pp[(size_t)j * NA]       = acc0[j];
    pp[(size_t)j * NA + 16]  = acc1[j];
    pp[(size_t)j * NA + 32]  = acc2[j];
    pp[(size_t)j * NA + 48]  = acc3[j];
  }
}

// ---------------- argmax (redundant per slice) + res/rec update + res bf16 refresh ----------------
__global__ __launch_bounds__(256) void update_kernel(float* __restrict__ res,
                                                     float* __restrict__ rec,
                                                     const float* __restrict__ atoms,
                                                     const float* __restrict__ rnorm,
                                                     const float* __restrict__ partials,
                                                     unsigned short* __restrict__ resH,
                                                     unsigned short* __restrict__ resL) {
  const int slice = blockIdx.x;   // 0..USLICE-1
  const int b = blockIdx.y;
  const int t = threadIdx.x;
  __shared__ float svals[256];
  __shared__ int sidx[256];
  float best = -INFINITY; int bi = 0;
  for (int a = t; a < NA; a += 256) {     // a = t, t+256 : ascending keeps first-max
    float d = 0.f;
    #pragma unroll 5
    for (int s = 0; s < NSLICE; ++s) d += partials[((size_t)s * NB + b) * NA + a];
    if (d > best) { best = d; bi = a; }
  }
  svals[t] = best; sidx[t] = bi; __syncthreads();
  for (int st = 128; st > 0; st >>= 1) {
    if (t < st) {
      const float v2 = svals[t + st]; const int i2 = sidx[t + st];
      if (v2 > svals[t] || (v2 == svals[t] && i2 < sidx[t])) { svals[t] = v2; sidx[t] = i2; }
    }
    __syncthreads();
  }
  const int idx = sidx[0];
  const float rn = rnorm[idx];
  // best = an[idx] .* res ; res -= best ; rec += best   (fp32 exact, this block's k-slice)
  const float2* arow = (const float2*)(atoms + (size_t)idx * LFREQ);
  float2* rrow = (float2*)(res + (size_t)b * RSTR);
  float2* crow = (float2*)(rec + (size_t)b * RSTR);
  unsigned short* hrow = resH + (size_t)b * KPS;
  unsigned short* lrow = resL + (size_t)b * KPS;
  const int i0 = slice * 2049;
  const int i1 = min(i0 + 2049, LFREQ / 2 + 1);   // 16385 float2 total
  for (int i = i0 + t; i < i1; i += 256) {
    const float2 r = rrow[i], a2 = arow[i], cc = crow[i];
    const float bx = a2.x * rn * r.x;
    const float by = a2.y * rn * r.y;
    const float nx = r.x - bx, ny = r.y - by;
    rrow[i] = make_float2(nx, ny);
    crow[i] = make_float2(cc.x + bx, cc.y + by);
    const int k = i << 1;
    const unsigned short hx = f2bf(nx), hy = f2bf(ny);
    hrow[k] = hx;     hrow[k + 1] = hy;
    lrow[k] = f2bf(nx - bf2f(hx));
    lrow[k + 1] = f2bf(ny - bf2f(hy));
  }
}

// ---------------- strip padding: res(ws, stride RSTR) -> out2 (contiguous 64x32770) ----------------
__global__ __launch_bounds__(256) void copy_res_kernel(const float* __restrict__ res,
                                                       float* __restrict__ out2) {
  const int b = blockIdx.x, t = threadIdx.x;
  const float* src = res + (size_t)b * RSTR;
  float* dst = out2 + (size_t)b * LFREQ;
  for (int k = t; k < LFREQ; k += 256) dst[k] = src[k];
}

extern "C" void kernel_launch(void* const* d_in, const int* in_sizes, int n_in,
                              void* d_out, int out_size, void* d_ws, size_t ws_size,
                              hipStream_t stream) {
  const float* x = (const float*)d_in[0];      // (64,1,32768)
  const float* atoms = (const float*)d_in[1];  // (1,512,32770)
  float* out = (float*)d_out;

  float* res = (float*)d_ws;                             // 64*32772 f32
  float* rec = res + (size_t)NB * RSTR;                  // 64*32772 f32
  float* rnorm = rec + (size_t)NB * RSTR;                // 512
  float* partials = rnorm + NA;                          // 65*64*512 f32
  unsigned short* resH = (unsigned short*)(partials + (size_t)NSLICE * NB * NA);
  unsigned short* resL = resH + (size_t)NB * KPS;
  unsigned short* anH  = resL + (size_t)NB * KPS;
  unsigned short* anL  = anH + (size_t)NA * KPS;

  hipMemsetAsync(rec, 0, (size_t)NB * RSTR * sizeof(float), stream);
  an_convert_kernel<<<NA, 256, 0, stream>>>(atoms, rnorm, anH, anL);
  fft_fwd_kernel<<<NB, 1024, MH * sizeof(float2), stream>>>(x, res);
  res_convert_kernel<<<NB, 256, 0, stream>>>(res, resH, resL);

  for (int it = 0; it < NITER; ++it) {
    dots_mfma_kernel<<<dim3(NSLICE, 8), 256, 0, stream>>>(resH, resL, anH, anL, partials);
    update_kernel<<<dim3(USLICE, NB), 256, 0, stream>>>(res, rec, atoms, rnorm, partials,
                                                        resH, resL);
  }

  fft_inv_kernel<<<NB, 1024, MH * sizeof(float2), stream>>>(rec, out);
  copy_res_kernel<<<NB, 256, 0, stream>>>(res, out + (size_t)NB * NSAMP);
}

// Round 3
// 3010.245 us; speedup vs baseline: 1.7427x; 1.6778x over previous
//
#include <hip/hip_runtime.h>
#include <math.h>

#define NSAMP 32768      // time-domain samples
#define MH    16384      // half-size complex FFT length
#define LFREQ 32770      // rfft concat(re,im) length = 2*(NSAMP/2+1)
#define NRE   16385      // number of rfft bins
#define NB    64         // batches
#define NA    512        // atoms
#define NITER 64
#define RSTR  32772      // padded row stride for fp32 res/rec in ws

#define KPS    33280     // bf16 row stride = 65*512 (zero-padded past LFREQ)
#define NSLICE 65        // k-slices for dots (512 k each, 128 per wave)
#define USLICE 8         // update kernel k-split
#define NCH    4097      // ceil(LFREQ/8) 8-float chunks per row

typedef __attribute__((ext_vector_type(8))) short bf16x8;
typedef __attribute__((ext_vector_type(8))) unsigned short u16x8;
typedef __attribute__((ext_vector_type(4))) float f32x4;

__device__ __forceinline__ int rev14(int v) { return (int)(__brev((unsigned)v) >> 18); }

__device__ __forceinline__ unsigned short f2bf(float f) {
  unsigned u = __float_as_uint(f);
  u = (u + 0x7fffu + ((u >> 16) & 1u)) >> 16;   // round-to-nearest-even
  return (unsigned short)u;
}
__device__ __forceinline__ float bf2f(unsigned short h) {
  return __uint_as_float(((unsigned)h) << 16);
}

// ---------------- forward rfft: x[b][32768] -> res[b][32770] (re|im concat) ----------------
__global__ __launch_bounds__(1024) void fft_fwd_kernel(const float* __restrict__ x,
                                                       float* __restrict__ res) {
  extern __shared__ float2 s[];   // 16384 complex = 128 KB
  const int b = blockIdx.x, t = threadIdx.x;
  const float2* xrow = (const float2*)(x + (size_t)b * NSAMP);
  for (int m = t; m < MH; m += 1024) s[m] = xrow[rev14(m)];
  __syncthreads();
  for (int st = 1; st <= 14; ++st) {
    const int half = 1 << (st - 1);
    const float fac = 3.14159265358979f / (float)half;
    for (int j = t; j < MH / 2; j += 1024) {
      const int blk = j >> (st - 1), pos = j & (half - 1);
      const int i0 = (blk << st) + pos, i1 = i0 + half;
      float sn, cs; __sincosf(fac * (float)pos, &sn, &cs);
      const float2 u = s[i0], v = s[i1];
      const float tr = cs * v.x + sn * v.y;
      const float ti = cs * v.y - sn * v.x;
      s[i0] = make_float2(u.x + tr, u.y + ti);
      s[i1] = make_float2(u.x - tr, u.y - ti);
    }
    __syncthreads();
  }
  float* rr = res + (size_t)b * RSTR;
  const float fac2 = 6.283185307179586f / (float)NSAMP;
  for (int k = t; k < MH; k += 1024) {
    if (k == 0) {
      const float2 z0 = s[0];
      rr[0] = z0.x + z0.y;      rr[NRE] = 0.f;
      rr[MH] = z0.x - z0.y;     rr[NRE + MH] = 0.f;
    } else {
      const float2 zk = s[k], zm = s[MH - k];
      const float xer = 0.5f * (zk.x + zm.x), xei = 0.5f * (zk.y - zm.y);
      const float p = 0.5f * (zk.y + zm.y);
      const float q = -0.5f * (zk.x - zm.x);
      float sn, cs; __sincosf(fac2 * (float)k, &sn, &cs);
      rr[k]       = xer + cs * p + sn * q;
      rr[NRE + k] = xei + cs * q - sn * p;
    }
  }
}

// ---------------- inverse rfft: rec[b][32770] -> out[b][32768] ----------------
__global__ __launch_bounds__(1024) void fft_inv_kernel(const float* __restrict__ rec,
                                                       float* __restrict__ out) {
  extern __shared__ float2 s[];
  const int b = blockIdx.x, t = threadIdx.x;
  const float* rr = rec + (size_t)b * RSTR;
  const float fac2 = 6.283185307179586f / (float)NSAMP;
  for (int m = t; m < MH; m += 1024) {
    const int k = rev14(m);
    float2 z;
    if (k == 0) {
      const float a0 = rr[0], aM = rr[MH];
      z = make_float2(0.5f * (a0 + aM), 0.5f * (a0 - aM));
    } else {
      const float xr_ = rr[k],       xi_ = rr[NRE + k];
      const float mr  = rr[MH - k],  mi  = rr[NRE + MH - k];
      const float xer = 0.5f * (xr_ + mr), xei = 0.5f * (xi_ - mi);
      const float er  = 0.5f * (xr_ - mr), ei  = 0.5f * (xi_ + mi);
      float sn, cs; __sincosf(fac2 * (float)k, &sn, &cs);
      const float xor_ = cs * er - sn * ei;
      const float xoi  = cs * ei + sn * er;
      z = make_float2(xer - xoi, xei + xor_);
    }
    s[m] = z;
  }
  __syncthreads();
  for (int st = 1; st <= 14; ++st) {
    const int half = 1 << (st - 1);
    const float fac = 3.14159265358979f / (float)half;
    for (int j = t; j < MH / 2; j += 1024) {
      const int blk = j >> (st - 1), pos = j & (half - 1);
      const int i0 = (blk << st) + pos, i1 = i0 + half;
      float sn, cs; __sincosf(fac * (float)pos, &sn, &cs);
      const float2 u = s[i0], v = s[i1];
      const float tr = cs * v.x - sn * v.y;
      const float ti = cs * v.y + sn * v.x;
      s[i0] = make_float2(u.x + tr, u.y + ti);
      s[i1] = make_float2(u.x - tr, u.y - ti);
    }
    __syncthreads();
  }
  const float inv = 1.0f / (float)MH;
  float2* orow = (float2*)(out + (size_t)b * NSAMP);
  for (int m = t; m < MH; m += 1024) {
    const float2 z = s[m];
    orow[m] = make_float2(z.x * inv, z.y * inv);
  }
}

// ---------------- atom norm + normalized bf16 hi/lo split (vectorized stores) ----------------
__global__ __launch_bounds__(256) void an_convert_kernel(const float* __restrict__ atoms,
                                                         float* __restrict__ rnorm,
                                                         unsigned short* __restrict__ anH,
                                                         unsigned short* __restrict__ anL) {
  const int a = blockIdx.x, t = threadIdx.x;
  const float* row = atoms + (size_t)a * LFREQ;
  const float2* row2 = (const float2*)row;
  float ss = 0.f;
  for (int i = t; i < LFREQ / 2; i += 256) {   // 16385 float2 exactly
    const float2 v = row2[i];
    ss += v.x * v.x + v.y * v.y;
  }
  __shared__ float red[256];
  red[t] = ss; __syncthreads();
  for (int st = 128; st > 0; st >>= 1) {
    if (t < st) red[t] += red[t + st];
    __syncthreads();
  }
  const float rn = 1.0f / sqrtf(red[0]);
  if (t == 0) rnorm[a] = rn;
  unsigned short* hrow = anH + (size_t)a * KPS;
  unsigned short* lrow = anL + (size_t)a * KPS;
  for (int c = t; c < KPS / 8; c += 256) {
    const int k0 = c * 8;
    float v[8];
    if (k0 + 8 <= LFREQ) {
      #pragma unroll
      for (int e = 0; e < 4; ++e) {
        const float2 p = *(const float2*)(row + k0 + 2 * e);
        v[2 * e] = p.x; v[2 * e + 1] = p.y;
      }
    } else {
      #pragma unroll
      for (int e = 0; e < 8; ++e) v[e] = (k0 + e < LFREQ) ? row[k0 + e] : 0.f;
    }
    u16x8 hv, lv;
    #pragma unroll
    for (int e = 0; e < 8; ++e) {
      const float sv = v[e] * rn;
      const unsigned short h = f2bf(sv);
      hv[e] = h;
      lv[e] = f2bf(sv - bf2f(h));
    }
    *(u16x8*)(hrow + k0) = hv;
    *(u16x8*)(lrow + k0) = lv;
  }
}

// ---------------- initial res -> bf16 hi/lo ----------------
__global__ __launch_bounds__(256) void res_convert_kernel(const float* __restrict__ res,
                                                          unsigned short* __restrict__ resH,
                                                          unsigned short* __restrict__ resL) {
  const int b = blockIdx.x, t = threadIdx.x;
  const float* row = res + (size_t)b * RSTR;
  unsigned short* hrow = resH + (size_t)b * KPS;
  unsigned short* lrow = resL + (size_t)b * KPS;
  for (int c = t; c < KPS / 8; c += 256) {
    const int k0 = c * 8;
    float v[8];
    if (k0 + 8 <= LFREQ) {
      #pragma unroll
      for (int e = 0; e < 2; ++e) {
        const float4 p = *(const float4*)(row + k0 + 4 * e);
        v[4 * e] = p.x; v[4 * e + 1] = p.y; v[4 * e + 2] = p.z; v[4 * e + 3] = p.w;
      }
    } else {
      #pragma unroll
      for (int e = 0; e < 8; ++e) v[e] = (k0 + e < LFREQ) ? row[k0 + e] : 0.f;
    }
    u16x8 hv, lv;
    #pragma unroll
    for (int e = 0; e < 8; ++e) {
      const unsigned short h = f2bf(v[e]);
      hv[e] = h;
      lv[e] = f2bf(v[e] - bf2f(h));
    }
    *(u16x8*)(hrow + k0) = hv;
    *(u16x8*)(lrow + k0) = lv;
  }
}

// ---------------- dots via split-bf16 MFMA, waves split K (no redundant loads) ----------------
// partials[s][b][a] = sum_{k in slice s} res[b][k] * an[a][k]
__global__ __launch_bounds__(256) void dots_mfma_kernel(const unsigned short* __restrict__ resH,
                                                        const unsigned short* __restrict__ resL,
                                                        const unsigned short* __restrict__ anH,
                                                        const unsigned short* __restrict__ anL,
                                                        float* __restrict__ partials) {
  __shared__ float lred[4 * 64 * 64];   // 64 KB: per-wave 64x64 partial tiles
  const int slice = blockIdx.x;   // 0..NSLICE-1, 512 k per block
  const int atile = blockIdx.y;   // 0..7, 64 atoms each
  const int t = threadIdx.x;
  const int wv = t >> 6, lane = t & 63;
  const int r16 = lane & 15;      // A row / B col within 16-group
  const int kg  = lane >> 4;      // k-group of 8
  // wave wv owns k-range [slice*512 + wv*128, +128)
  const size_t kbase = (size_t)slice * 512 + (size_t)wv * 128 + (size_t)kg * 8;

  const unsigned short* pAH = resH + (size_t)r16 * KPS + kbase;
  const unsigned short* pAL = resL + (size_t)r16 * KPS + kbase;
  const unsigned short* pBH = anH + (size_t)(atile * 64 + r16) * KPS + kbase;
  const unsigned short* pBL = anL + (size_t)(atile * 64 + r16) * KPS + kbase;

  f32x4 acc[4][4] = {};

  #pragma unroll
  for (int s = 0; s < 4; ++s) {
    const int ko = s * 32;
    bf16x8 aH[4], aL[4], bH[4], bL[4];
    #pragma unroll
    for (int i = 0; i < 4; ++i) {
      aH[i] = *(const bf16x8*)(pAH + (size_t)i * 16 * KPS + ko);
      aL[i] = *(const bf16x8*)(pAL + (size_t)i * 16 * KPS + ko);
    }
    #pragma unroll
    for (int j = 0; j < 4; ++j) {
      bH[j] = *(const bf16x8*)(pBH + (size_t)j * 16 * KPS + ko);
      bL[j] = *(const bf16x8*)(pBL + (size_t)j * 16 * KPS + ko);
    }
    #pragma unroll
    for (int i = 0; i < 4; ++i)
      #pragma unroll
      for (int j = 0; j < 4; ++j) {
        acc[i][j] = __builtin_amdgcn_mfma_f32_16x16x32_bf16(aH[i], bH[j], acc[i][j], 0, 0, 0);
        acc[i][j] = __builtin_amdgcn_mfma_f32_16x16x32_bf16(aH[i], bL[j], acc[i][j], 0, 0, 0);
        acc[i][j] = __builtin_amdgcn_mfma_f32_16x16x32_bf16(aL[i], bH[j], acc[i][j], 0, 0, 0);
      }
  }
  // D layout: row=(lane>>4)*4+e (batch), col=lane&15 (atom)
  #pragma unroll
  for (int i = 0; i < 4; ++i)
    #pragma unroll
    for (int j = 0; j < 4; ++j)
      #pragma unroll
      for (int e = 0; e < 4; ++e)
        lred[wv * 4096 + (i * 16 + kg * 4 + e) * 64 + j * 16 + r16] = acc[i][j][e];
  __syncthreads();
  for (int o = t; o < 4096; o += 256) {
    const float v = lred[o] + lred[4096 + o] + lred[8192 + o] + lred[12288 + o];
    partials[((size_t)slice * NB + (o >> 6)) * NA + (size_t)atile * 64 + (o & 63)] = v;
  }
}

// ---------------- reduce partials over slices + argmax (once per batch) ----------------
__global__ __launch_bounds__(256) void reduce_argmax_kernel(const float* __restrict__ partials,
                                                            int* __restrict__ bestidx) {
  const int b = blockIdx.x, t = threadIdx.x;
  float d0 = 0.f, d1 = 0.f;
  for (int s = 0; s < NSLICE; ++s) {
    const float* p = partials + ((size_t)s * NB + b) * NA;
    d0 += p[t];
    d1 += p[t + 256];
  }
  float best = d0; int bi = t;
  if (d1 > best) { best = d1; bi = t + 256; }   // strict > keeps smaller index
  __shared__ float sv[256]; __shared__ int si[256];
  sv[t] = best; si[t] = bi; __syncthreads();
  for (int st = 128; st > 0; st >>= 1) {
    if (t < st) {
      const float v2 = sv[t + st]; const int i2 = si[t + st];
      if (v2 > sv[t] || (v2 == sv[t] && i2 < si[t])) { sv[t] = v2; si[t] = i2; }
    }
    __syncthreads();
  }
  if (t == 0) bestidx[b] = si[0];
}

// ---------------- res/rec update + res bf16 refresh (vectorized) ----------------
__global__ __launch_bounds__(256) void update_kernel(float* __restrict__ res,
                                                     float* __restrict__ rec,
                                                     const float* __restrict__ atoms,
                                                     const float* __restrict__ rnorm,
                                                     const int* __restrict__ bestidx,
                                                     unsigned short* __restrict__ resH,
                                                     unsigned short* __restrict__ resL) {
  const int slice = blockIdx.x;   // 0..USLICE-1
  const int b = blockIdx.y;
  const int t = threadIdx.x;
  const int idx = bestidx[b];
  const float rn = rnorm[idx];
  const float* arow = atoms + (size_t)idx * LFREQ;
  float* rrow = res + (size_t)b * RSTR;
  float* crow = rec + (size_t)b * RSTR;
  unsigned short* hrow = resH + (size_t)b * KPS;
  unsigned short* lrow = resL + (size_t)b * KPS;
  const int c0 = slice * 513;
  const int c1 = min(c0 + 513, NCH);
  for (int c = c0 + t; c < c1; c += 256) {
    const int k0 = c * 8;
    if (k0 + 8 <= LFREQ) {
      float rv[8], av[8], cv[8];
      #pragma unroll
      for (int e = 0; e < 2; ++e) {
        const float4 q = *(const float4*)(rrow + k0 + 4 * e);
        rv[4 * e] = q.x; rv[4 * e + 1] = q.y; rv[4 * e + 2] = q.z; rv[4 * e + 3] = q.w;
        const float4 qc = *(const float4*)(crow + k0 + 4 * e);
        cv[4 * e] = qc.x; cv[4 * e + 1] = qc.y; cv[4 * e + 2] = qc.z; cv[4 * e + 3] = qc.w;
      }
      #pragma unroll
      for (int e = 0; e < 4; ++e) {
        const float2 p = *(const float2*)(arow + k0 + 2 * e);
        av[2 * e] = p.x; av[2 * e + 1] = p.y;
      }
      float nv[8];
      u16x8 hv, lv;
      #pragma unroll
      for (int e = 0; e < 8; ++e) {
        const float bx = av[e] * rn * rv[e];
        nv[e] = rv[e] - bx;
        cv[e] += bx;
        const unsigned short h = f2bf(nv[e]);
        hv[e] = h;
        lv[e] = f2bf(nv[e] - bf2f(h));
      }
      #pragma unroll
      for (int e = 0; e < 2; ++e) {
        *(float4*)(rrow + k0 + 4 * e) = make_float4(nv[4*e], nv[4*e+1], nv[4*e+2], nv[4*e+3]);
        *(float4*)(crow + k0 + 4 * e) = make_float4(cv[4*e], cv[4*e+1], cv[4*e+2], cv[4*e+3]);
      }
      *(u16x8*)(hrow + k0) = hv;
      *(u16x8*)(lrow + k0) = lv;
    } else {
      for (int e = 0; e < 8; ++e) {
        const int k = k0 + e;
        if (k < LFREQ) {
          const float r = rrow[k], a = arow[k], cc = crow[k];
          const float bx = a * rn * r;
          const float nx = r - bx;
          rrow[k] = nx;
          crow[k] = cc + bx;
          const unsigned short h = f2bf(nx);
          hrow[k] = h;
          lrow[k] = f2bf(nx - bf2f(h));
        }
      }
    }
  }
}

// ---------------- strip padding: res(ws, stride RSTR) -> out2 (contiguous 64x32770) ----------------
__global__ __launch_bounds__(256) void copy_res_kernel(const float* __restrict__ res,
                                                       float* __restrict__ out2) {
  const int b = blockIdx.x, t = threadIdx.x;
  const float2* src = (const float2*)(res + (size_t)b * RSTR);
  float* dst = out2 + (size_t)b * LFREQ;
  for (int i = t; i < LFREQ / 2; i += 256) {    // 16385 float2 exactly
    const float2 v = src[i];
    dst[2 * i] = v.x; dst[2 * i + 1] = v.y;
  }
}

extern "C" void kernel_launch(void* const* d_in, const int* in_sizes, int n_in,
                              void* d_out, int out_size, void* d_ws, size_t ws_size,
                              hipStream_t stream) {
  const float* x = (const float*)d_in[0];      // (64,1,32768)
  const float* atoms = (const float*)d_in[1];  // (1,512,32770)
  float* out = (float*)d_out;

  float* res = (float*)d_ws;                             // 64*32772 f32
  float* rec = res + (size_t)NB * RSTR;                  // 64*32772 f32
  float* rnorm = rec + (size_t)NB * RSTR;                // 512
  float* partials = rnorm + NA;                          // 65*64*512 f32
  int* bestidx = (int*)(partials + (size_t)NSLICE * NB * NA);   // 64
  unsigned short* resH = (unsigned short*)(bestidx + 64);
  unsigned short* resL = resH + (size_t)NB * KPS;
  unsigned short* anH  = resL + (size_t)NB * KPS;
  unsigned short* anL  = anH + (size_t)NA * KPS;

  hipMemsetAsync(rec, 0, (size_t)NB * RSTR * sizeof(float), stream);
  an_convert_kernel<<<NA, 256, 0, stream>>>(atoms, rnorm, anH, anL);
  fft_fwd_kernel<<<NB, 1024, MH * sizeof(float2), stream>>>(x, res);
  res_convert_kernel<<<NB, 256, 0, stream>>>(res, resH, resL);

  for (int it = 0; it < NITER; ++it) {
    dots_mfma_kernel<<<dim3(NSLICE, 8), 256, 0, stream>>>(resH, resL, anH, anL, partials);
    reduce_argmax_kernel<<<NB, 256, 0, stream>>>(partials, bestidx);
    update_kernel<<<dim3(USLICE, NB), 256, 0, stream>>>(res, rec, atoms, rnorm, bestidx,
                                                        resH, resL);
  }

  fft_inv_kernel<<<NB, 1024, MH * sizeof(float2), stream>>>(rec, out);
  copy_res_kernel<<<NB, 256, 0, stream>>>(res, out + (size_t)NB * NSAMP);
}